// Round 3
// baseline (236.452 us; speedup 1.0000x reference)
//
#include <hip/hip_runtime.h>
#include <math.h>

#define NTILES 64
#define TPC 8
#define NCLUST 8
#define GRID_SZ 16
#define DIM 512
#define DHID 128
#define NTOK 2048
#define LN_EPS 1e-5f
#define TB 8          // tokens per k_ffn chunk
#define MAXCH 8       // grid.y chunks for k_ffn

static __device__ __forceinline__ float fsign(float v) {
    return (v > 0.f) ? 1.f : ((v < 0.f) ? -1.f : 0.f);
}

// Stage 1 of tile signatures: partial sums over 16 dh each.
// grid (NTILES, 8), 256 threads. Also zeros counts.
__global__ __launch_bounds__(256) void k_sig_part(const float* __restrict__ Wd,
                                                  float* __restrict__ psum,
                                                  int* __restrict__ counts) {
    int t = blockIdx.x, part = blockIdx.y, tid = threadIdx.x;
    if (t == 0 && part == 0 && tid < NTILES) counts[tid] = 0;
    const float* base = Wd + ((size_t)t * DHID + part * 16) * DIM;
    #pragma unroll
    for (int k = 0; k < 2; ++k) {
        int d = tid + k * 256;
        float s = 0.f;
        #pragma unroll
        for (int j = 0; j < 16; ++j) s += base[(size_t)j * DIM + d];
        psum[((size_t)t * 8 + part) * DIM + d] = s;
    }
}

// Stage 2: tile_sigs + cluster_sigs. grid (NCLUST, 2), 256 threads.
__global__ __launch_bounds__(256) void k_sigs(const float* __restrict__ psum,
                                              float* __restrict__ tile_sigs,
                                              float* __restrict__ cluster_sigs) {
    int c = blockIdx.x;
    int d = blockIdx.y * 256 + threadIdx.x;
    float csum = 0.f;
    #pragma unroll
    for (int k = 0; k < TPC; ++k) {
        int t = c * TPC + k;
        float s = 0.f;
        #pragma unroll
        for (int p = 0; p < 8; ++p) s += psum[((size_t)t * 8 + p) * DIM + d];
        float sg = fsign(s);
        tile_sigs[(size_t)t * DIM + d] = sg;
        csum += sg;
    }
    cluster_sigs[(size_t)c * DIM + d] = fsign(csum);
}

// 4 waves per block, one token per wave: LayerNorm + routing + list build
__global__ __launch_bounds__(256) void k_ln_route(const float* __restrict__ x,
                                                  const float* __restrict__ gamma,
                                                  const float* __restrict__ beta,
                                                  const float* __restrict__ tile_sigs,
                                                  const float* __restrict__ cluster_sigs,
                                                  float* __restrict__ xn_out,
                                                  int* __restrict__ counts,
                                                  int* __restrict__ list) {
    int n = blockIdx.x * 4 + (threadIdx.x >> 6);
    int lane = threadIdx.x & 63;
    const float* xr = x + (size_t)n * DIM;

    float v[8];
    float sum = 0.f;
    #pragma unroll
    for (int j = 0; j < 8; ++j) { float t = xr[lane + 64 * j]; v[j] = t; sum += t; }
    #pragma unroll
    for (int off = 32; off; off >>= 1) sum += __shfl_xor(sum, off);
    float mu = sum * (1.f / DIM);

    float sq = 0.f;
    #pragma unroll
    for (int j = 0; j < 8; ++j) { float t = v[j] - mu; sq += t * t; }
    #pragma unroll
    for (int off = 32; off; off >>= 1) sq += __shfl_xor(sq, off);
    float rs = rsqrtf(sq * (1.f / DIM) + LN_EPS);

    float sg[8];
    #pragma unroll
    for (int j = 0; j < 8; ++j) {
        int d = lane + 64 * j;
        float xv = (v[j] - mu) * rs * gamma[d] + beta[d];
        xn_out[(size_t)n * DIM + d] = xv;
        sg[j] = fsign(xv);
    }

    // cluster argmax (scores exact integers in f32; strict > ascending = first-index tie-break)
    int best_c = 0; float best = -1e30f;
    for (int c = 0; c < NCLUST; ++c) {
        float s = 0.f;
        #pragma unroll
        for (int j = 0; j < 8; ++j) s += sg[j] * cluster_sigs[(size_t)c * DIM + lane + 64 * j];
        #pragma unroll
        for (int off = 32; off; off >>= 1) s += __shfl_xor(s, off);
        if (s > best) { best = s; best_c = c; }
    }
    int bt = best_c * TPC; float bts = -1e30f;
    for (int k = 0; k < TPC; ++k) {
        int t = best_c * TPC + k;
        float s = 0.f;
        #pragma unroll
        for (int j = 0; j < 8; ++j) s += sg[j] * tile_sigs[(size_t)t * DIM + lane + 64 * j];
        #pragma unroll
        for (int off = 32; off; off >>= 1) s += __shfl_xor(s, off);
        if (s > bts) { bts = s; bt = t; }
    }

    if (lane == 0) {
        int slot = atomicAdd(&counts[bt], 1);
        list[(size_t)bt * NTOK + slot] = n;
    }
}

// grid (tile, chunk): 1024 threads, TB=8 tokens per chunk.
// down: thread=(dh=tid>>3, q=tid&7): d-interleaved 8-way -> wave loads = 8x128B runs
// up:   thread=(du=tid>>1, s=tid&1): dh-interleaved 2-way, shfl_xor(1) combine
__global__ __launch_bounds__(1024, 4) void k_ffn(const float* __restrict__ x,
                                                 const float* __restrict__ xn,
                                                 const float* __restrict__ Wd,
                                                 const float* __restrict__ sb,
                                                 const float* __restrict__ ss,
                                                 const float* __restrict__ Wu,
                                                 const float* __restrict__ scale,
                                                 const int* __restrict__ counts,
                                                 const int* __restrict__ list,
                                                 float* __restrict__ out) {
    int t = blockIdx.x;
    int cnt = counts[t];
    if ((int)blockIdx.y * TB >= cnt) return;

    __shared__ float xn_s[TB][DIM];        // 16 KB
    __shared__ float hp_s[TB][DHID][8];    // 32 KB
    __shared__ float hs_s[TB][DHID];       // 4 KB
    __shared__ int toks[TB];

    int tid = threadIdx.x;
    float sc_t = scale[t];
    const float* sbt = sb + (size_t)t * DHID * GRID_SZ;
    const float* sst = ss + (size_t)t * DHID * GRID_SZ;

    int q  = tid & 7;                      // down: d-interleave slot
    int dh = tid >> 3;                     // down: hidden row
    const float* wd = Wd + ((size_t)t * DHID + dh) * DIM;
    int s  = tid & 1;                      // up: dh-interleave slot
    int du = tid >> 1;                     // up: output d
    const float* wu = Wu + ((size_t)t * DIM + du) * DHID;

    for (int j0 = blockIdx.y; j0 * TB < cnt; j0 += MAXCH) {
        int base = j0 * TB;
        int m = min(TB, cnt - base);
        if (tid < TB) toks[tid] = (tid < m) ? list[(size_t)t * NTOK + base + tid] : -1;

        // stage xn for TB tokens (zeros for padding): 1024 float4, one per thread
        {
            int p = tid >> 7;
            int d4 = (tid & 127) * 4;
            int tok = (p < m) ? list[(size_t)t * NTOK + base + p] : -1;
            float4 v = {0.f, 0.f, 0.f, 0.f};
            if (tok >= 0) v = *(const float4*)(xn + (size_t)tok * DIM + d4);
            *(float4*)(&xn_s[p][d4]) = v;
        }
        __syncthreads();

        // down-projection: thread reduces its 64 interleaved d for row dh, 8 tokens
        float acc[TB];
        #pragma unroll
        for (int p = 0; p < TB; ++p) acc[p] = 0.f;
        #pragma unroll
        for (int it = 0; it < 16; ++it) {
            int d = it * 32 + q * 4;
            float4 w = *(const float4*)(wd + d);
            #pragma unroll
            for (int p = 0; p < TB; ++p) {
                float4 xv = *(const float4*)(&xn_s[p][d]);
                acc[p] += w.x * xv.x + w.y * xv.y + w.z * xv.z + w.w * xv.w;
            }
        }
        #pragma unroll
        for (int p = 0; p < TB; ++p) hp_s[p][dh][q] = acc[p];   // addr = p*1024+tid: conflict-free
        __syncthreads();

        // combine 8 partials + spline: 1024 elems, one per thread
        {
            int p = tid >> 7, dd = tid & 127;
            float4 a = *(const float4*)(&hp_s[p][dd][0]);
            float4 b = *(const float4*)(&hp_s[p][dd][4]);
            float h = ((a.x + a.y) + (a.z + a.w)) + ((b.x + b.y) + (b.z + b.w));
            float hn = 1.f / (1.f + expf(-h));
            float g = hn * (float)GRID_SZ;
            int idx = (int)g;
            idx = (idx > GRID_SZ - 1) ? GRID_SZ - 1 : (idx < 0 ? 0 : idx);
            float lp = g - (float)idx;
            hs_s[p][dd] = sbt[dd * GRID_SZ + idx] + sst[dd * GRID_SZ + idx] * lp;
        }
        __syncthreads();

        // up-projection: thread reduces its 64 interleaved dh for output du, 8 tokens
        float acu[TB];
        #pragma unroll
        for (int p = 0; p < TB; ++p) acu[p] = 0.f;
        #pragma unroll
        for (int it = 0; it < 16; ++it) {
            int dd = it * 8 + s * 4;
            float4 w = *(const float4*)(wu + dd);
            #pragma unroll
            for (int p = 0; p < TB; ++p) {
                float4 hv = *(const float4*)(&hs_s[p][dd]);
                acu[p] += w.x * hv.x + w.y * hv.y + w.z * hv.z + w.w * hv.w;
            }
        }
        #pragma unroll
        for (int p = 0; p < TB; ++p) acu[p] += __shfl_xor(acu[p], 1);
        if (s == 0) {
            for (int p = 0; p < m; ++p) {
                int tok = toks[p];
                out[(size_t)tok * DIM + du] = x[(size_t)tok * DIM + du] + acu[p] * sc_t;
            }
        }
        __syncthreads();
    }
}

extern "C" void kernel_launch(void* const* d_in, const int* in_sizes, int n_in,
                              void* d_out, int out_size, void* d_ws, size_t ws_size,
                              hipStream_t stream) {
    const float* x     = (const float*)d_in[0];
    const float* gamma = (const float*)d_in[1];
    const float* beta  = (const float*)d_in[2];
    const float* Wd    = (const float*)d_in[3];
    const float* sb    = (const float*)d_in[4];
    const float* ss    = (const float*)d_in[5];
    const float* Wu    = (const float*)d_in[6];
    const float* scale = (const float*)d_in[7];
    float* out = (float*)d_out;

    // workspace layout
    float* psum         = (float*)d_ws;                          // 64*8*512 f
    float* tile_sigs    = psum + (size_t)NTILES * 8 * DIM;       // 32K f
    float* cluster_sigs = tile_sigs + NTILES * DIM;              // 4K f
    float* xn           = cluster_sigs + NCLUST * DIM;           // 1M f
    int*   counts       = (int*)(xn + (size_t)NTOK * DIM);       // 64 ints
    int*   list         = counts + NTILES;                       // 128K ints

    k_sig_part<<<dim3(NTILES, 8), 256, 0, stream>>>(Wd, psum, counts);
    k_sigs<<<dim3(NCLUST, 2), 256, 0, stream>>>(psum, tile_sigs, cluster_sigs);
    k_ln_route<<<NTOK / 4, 256, 0, stream>>>(x, gamma, beta, tile_sigs, cluster_sigs, xn, counts, list);
    k_ffn<<<dim3(NTILES, MAXCH), 1024, 0, stream>>>(x, xn, Wd, sb, ss, Wu, scale, counts, list, out);
}

// Round 4
// 65.821 us; speedup vs baseline: 3.5924x; 3.5924x over previous
//
#include <hip/hip_runtime.h>
#include <math.h>

#define NTILES 64
#define TPC 8
#define NCLUST 8
#define GRID_SZ 16
#define DIM 512
#define DHID 128
#define NTOK 2048
#define LN_EPS 1e-5f
#define TB 8              // tokens per chunk
#define NCHUNK_MAX 320    // sum ceil(cnt/TB) <= 2048/8 + 64 = 312 <= 320 = 8*40

static __device__ __forceinline__ float fsign(float v) {
    return (v > 0.f) ? 1.f : ((v < 0.f) ? -1.f : 0.f);
}

// Partial column sums of Wd: grid (NTILES, 4), 512 threads, 32 dh rows each.
__global__ __launch_bounds__(512) void k_sig_part(const float* __restrict__ Wd,
                                                  float* __restrict__ psum) {
    int t = blockIdx.x, part = blockIdx.y, tid = threadIdx.x;
    const float* base = Wd + ((size_t)t * DHID + part * 32) * DIM + tid;
    float s = 0.f;
    #pragma unroll 8
    for (int j = 0; j < 32; ++j) s += base[(size_t)j * DIM];
    psum[((size_t)t * 4 + part) * DIM + tid] = s;
}

// tile_sigs + cluster_sigs + zero counts. grid (NCLUST), 512 threads.
__global__ __launch_bounds__(512) void k_csig(const float* __restrict__ psum,
                                              float* __restrict__ tile_sigs,
                                              float* __restrict__ cluster_sigs,
                                              int* __restrict__ counts) {
    int c = blockIdx.x, d = threadIdx.x;
    if (c == 0 && d < NTILES) counts[d] = 0;
    float csum = 0.f;
    #pragma unroll
    for (int k = 0; k < TPC; ++k) {
        int t = c * TPC + k;
        float s = psum[((size_t)t * 4 + 0) * DIM + d] + psum[((size_t)t * 4 + 1) * DIM + d]
                + psum[((size_t)t * 4 + 2) * DIM + d] + psum[((size_t)t * 4 + 3) * DIM + d];
        float sg = fsign(s);
        tile_sigs[(size_t)t * DIM + d] = sg;
        csum += sg;
    }
    cluster_sigs[(size_t)c * DIM + d] = fsign(csum);
}

// 4 waves per block, one token per wave: LayerNorm + routing + list build
__global__ __launch_bounds__(256) void k_ln_route(const float* __restrict__ x,
                                                  const float* __restrict__ gamma,
                                                  const float* __restrict__ beta,
                                                  const float* __restrict__ tile_sigs,
                                                  const float* __restrict__ cluster_sigs,
                                                  float* __restrict__ xn_out,
                                                  int* __restrict__ counts,
                                                  int* __restrict__ list) {
    int n = blockIdx.x * 4 + (threadIdx.x >> 6);
    int lane = threadIdx.x & 63;
    const float* xr = x + (size_t)n * DIM;

    float v[8];
    float sum = 0.f;
    #pragma unroll
    for (int j = 0; j < 8; ++j) { float t = xr[lane + 64 * j]; v[j] = t; sum += t; }
    #pragma unroll
    for (int off = 32; off; off >>= 1) sum += __shfl_xor(sum, off);
    float mu = sum * (1.f / DIM);

    float sq = 0.f;
    #pragma unroll
    for (int j = 0; j < 8; ++j) { float t = v[j] - mu; sq += t * t; }
    #pragma unroll
    for (int off = 32; off; off >>= 1) sq += __shfl_xor(sq, off);
    float rs = rsqrtf(sq * (1.f / DIM) + LN_EPS);

    float sg[8];
    #pragma unroll
    for (int j = 0; j < 8; ++j) {
        int d = lane + 64 * j;
        float xv = (v[j] - mu) * rs * gamma[d] + beta[d];
        xn_out[(size_t)n * DIM + d] = xv;
        sg[j] = fsign(xv);
    }

    // cluster argmax (scores exact integers in f32; strict > ascending = first-index tie-break)
    int best_c = 0; float best = -1e30f;
    for (int c = 0; c < NCLUST; ++c) {
        float s = 0.f;
        #pragma unroll
        for (int j = 0; j < 8; ++j) s += sg[j] * cluster_sigs[(size_t)c * DIM + lane + 64 * j];
        #pragma unroll
        for (int off = 32; off; off >>= 1) s += __shfl_xor(s, off);
        if (s > best) { best = s; best_c = c; }
    }
    int bt = best_c * TPC; float bts = -1e30f;
    for (int k = 0; k < TPC; ++k) {
        int t = best_c * TPC + k;
        float s = 0.f;
        #pragma unroll
        for (int j = 0; j < 8; ++j) s += sg[j] * tile_sigs[(size_t)t * DIM + lane + 64 * j];
        #pragma unroll
        for (int off = 32; off; off >>= 1) s += __shfl_xor(s, off);
        if (s > bts) { bts = s; bt = t; }
    }

    if (lane == 0) {
        int slot = atomicAdd(&counts[bt], 1);
        list[(size_t)bt * NTOK + slot] = n;
    }
}

// Build chunk descriptors: one wave. desc[i] = (tile<<16)|chunk_idx, -1 past end.
__global__ __launch_bounds__(64) void k_chunks(const int* __restrict__ counts,
                                               int* __restrict__ desc) {
    int lane = threadIdx.x;
    int nck = (counts[lane] + TB - 1) / TB;
    int pre = nck;
    #pragma unroll
    for (int off = 1; off < 64; off <<= 1) {
        int v = __shfl_up(pre, off);
        if (lane >= off) pre += v;
    }
    int total = __shfl(pre, 63);   // inclusive at lane 63 == grand total
    pre -= nck;                    // exclusive prefix
    for (int i = lane; i < NCHUNK_MAX; i += 64)
        if (i >= total) desc[i] = -1;
    for (int j = 0; j < nck; ++j)
        desc[pre + j] = (lane << 16) | j;
}

// One chunk (8 tokens of one tile) per block. 512 threads.
// down: thread=(dh=tid>>2, q=tid&3), d=it*16+q*4  -> wave loads 16 rows x 64B runs
// up:   thread=(du0=tid>>2, q=tid&3), dh=it*16+q*4, 4 du-groups; shfl_xor(1,2) combine
__global__ __launch_bounds__(512) void k_ffn(const float* __restrict__ x,
                                             const float* __restrict__ xn,
                                             const float* __restrict__ Wd,
                                             const float* __restrict__ sb,
                                             const float* __restrict__ ss,
                                             const float* __restrict__ Wu,
                                             const float* __restrict__ scale,
                                             const int* __restrict__ counts,
                                             const int* __restrict__ list,
                                             const int* __restrict__ desc,
                                             float* __restrict__ out) {
    int b = blockIdx.x;
    int dsc = desc[(b & 7) * (NCHUNK_MAX / 8) + (b >> 3)];  // same-tile chunks -> same XCD
    if (dsc < 0) return;
    int t = dsc >> 16;
    int base = (dsc & 0xffff) * TB;
    int cnt = counts[t];
    int m = min(TB, cnt - base);

    __shared__ float xn_s[TB][DIM];        // 16 KB
    __shared__ float hp_s[TB][DHID][4];    // 16 KB
    __shared__ float hs_s[TB][DHID];       // 4 KB
    __shared__ int toks[TB];

    int tid = threadIdx.x;
    float sc_t = scale[t];
    const float* sbt = sb + (size_t)t * DHID * GRID_SZ;
    const float* sst = ss + (size_t)t * DHID * GRID_SZ;

    if (tid < TB) toks[tid] = (tid < m) ? list[(size_t)t * NTOK + base + tid] : -1;

    // stage xn for TB tokens (zeros for padding): 1024 float4, 2 per thread
    #pragma unroll
    for (int k = 0; k < 2; ++k) {
        int f = tid + k * 512;
        int p = f >> 7;
        int d4 = (f & 127) * 4;
        int tok = (p < m) ? list[(size_t)t * NTOK + base + p] : -1;
        float4 v = {0.f, 0.f, 0.f, 0.f};
        if (tok >= 0) v = *(const float4*)(xn + (size_t)tok * DIM + d4);
        *(float4*)(&xn_s[p][d4]) = v;
    }
    __syncthreads();

    // down-projection
    int q = tid & 3;
    int dh = tid >> 2;
    const float* wd = Wd + ((size_t)t * DHID + dh) * DIM;
    float acc[TB];
    #pragma unroll
    for (int p = 0; p < TB; ++p) acc[p] = 0.f;
    #pragma unroll 8
    for (int it = 0; it < 32; ++it) {
        int d = it * 16 + q * 4;
        float4 w = *(const float4*)(wd + d);
        #pragma unroll
        for (int p = 0; p < TB; ++p) {
            float4 xv = *(const float4*)(&xn_s[p][d]);
            acc[p] += w.x * xv.x + w.y * xv.y + w.z * xv.z + w.w * xv.w;
        }
    }
    #pragma unroll
    for (int p = 0; p < TB; ++p) hp_s[p][dh][q] = acc[p];   // addr = p*512 + tid
    __syncthreads();

    // combine 4 partials + spline: 1024 elems, 2 per thread
    #pragma unroll
    for (int k = 0; k < 2; ++k) {
        int e = tid + k * 512;
        int p = e >> 7, dd = e & 127;
        float4 a = *(const float4*)(&hp_s[p][dd][0]);
        float h = (a.x + a.y) + (a.z + a.w);
        float hn = 1.f / (1.f + expf(-h));
        float g = hn * (float)GRID_SZ;
        int idx = (int)g;
        idx = (idx > GRID_SZ - 1) ? GRID_SZ - 1 : (idx < 0 ? 0 : idx);
        float lp = g - (float)idx;
        hs_s[p][dd] = sbt[dd * GRID_SZ + idx] + sst[dd * GRID_SZ + idx] * lp;
    }
    __syncthreads();

    // up-projection: 4 du-groups of 128 outputs
    int du0 = tid >> 2;
    #pragma unroll
    for (int g = 0; g < 4; ++g) {
        int du = g * 128 + du0;
        const float* wu = Wu + ((size_t)t * DIM + du) * DHID;
        float acu[TB];
        #pragma unroll
        for (int p = 0; p < TB; ++p) acu[p] = 0.f;
        #pragma unroll
        for (int it = 0; it < 8; ++it) {
            int dd = it * 16 + q * 4;
            float4 w = *(const float4*)(wu + dd);
            #pragma unroll
            for (int p = 0; p < TB; ++p) {
                float4 hv = *(const float4*)(&hs_s[p][dd]);
                acu[p] += w.x * hv.x + w.y * hv.y + w.z * hv.z + w.w * hv.w;
            }
        }
        #pragma unroll
        for (int p = 0; p < TB; ++p) {
            acu[p] += __shfl_xor(acu[p], 1);
            acu[p] += __shfl_xor(acu[p], 2);
        }
        // 4 lanes of each group store 4 different tokens in parallel
        #pragma unroll
        for (int pp = 0; pp < 2; ++pp) {
            int p = pp * 4 + q;
            if (p < m) {
                int tok = toks[p];
                out[(size_t)tok * DIM + du] = x[(size_t)tok * DIM + du] + acu[p] * sc_t;
            }
        }
    }
}

extern "C" void kernel_launch(void* const* d_in, const int* in_sizes, int n_in,
                              void* d_out, int out_size, void* d_ws, size_t ws_size,
                              hipStream_t stream) {
    const float* x     = (const float*)d_in[0];
    const float* gamma = (const float*)d_in[1];
    const float* beta  = (const float*)d_in[2];
    const float* Wd    = (const float*)d_in[3];
    const float* sb    = (const float*)d_in[4];
    const float* ss    = (const float*)d_in[5];
    const float* Wu    = (const float*)d_in[6];
    const float* scale = (const float*)d_in[7];
    float* out = (float*)d_out;

    // workspace layout
    float* psum         = (float*)d_ws;                          // 64*4*512 f
    float* tile_sigs    = psum + (size_t)NTILES * 4 * DIM;       // 32K f
    float* cluster_sigs = tile_sigs + NTILES * DIM;              // 4K f
    float* xn           = cluster_sigs + NCLUST * DIM;           // 1M f
    int*   counts       = (int*)(xn + (size_t)NTOK * DIM);       // 64 ints
    int*   list         = counts + NTILES;                       // 128K ints
    int*   desc         = list + (size_t)NTILES * NTOK;          // 320 ints

    k_sig_part<<<dim3(NTILES, 4), 512, 0, stream>>>(Wd, psum);
    k_csig<<<NCLUST, 512, 0, stream>>>(psum, tile_sigs, cluster_sigs, counts);
    k_ln_route<<<NTOK / 4, 256, 0, stream>>>(x, gamma, beta, tile_sigs, cluster_sigs, xn, counts, list);
    k_chunks<<<1, 64, 0, stream>>>(counts, desc);
    k_ffn<<<NCHUNK_MAX, 512, 0, stream>>>(x, xn, Wd, sb, ss, Wu, scale, counts, list, desc, out);
}